// Round 3
// baseline (853.314 us; speedup 1.0000x reference)
//
#include <hip/hip_runtime.h>
#include <hip/hip_bf16.h>
#include <hip/hip_fp16.h>
#include <math.h>

#define NROW 8192
#define DIM  128
#define RSTRIPE 16
#define NSTRIPE (NROW / RSTRIPE)   // 512

typedef short bf16x8 __attribute__((ext_vector_type(8)));
typedef float f32x4  __attribute__((ext_vector_type(4)));
typedef _Float16 half8 __attribute__((ext_vector_type(8)));
typedef _Float16 half2v __attribute__((ext_vector_type(2)));

__device__ inline ushort f2bf(float x) { __hip_bfloat16 b = __float2bfloat16(x); return *(ushort*)&b; }
__device__ inline float  bf2f(ushort u) { __hip_bfloat16 b; *(ushort*)&b = u; return __bfloat162float(b); }

// ---------------- row normalize + split into bf16 hi/lo ----------------
__global__ void rownorm_kernel(const float* __restrict__ X,
                               ushort* __restrict__ dn_hi, ushort* __restrict__ dn_lo) {
    int row = blockIdx.x;
    int lane = threadIdx.x;            // 64 lanes
    const float2* x2 = reinterpret_cast<const float2*>(X + (size_t)row * DIM);
    float2 v = x2[lane];
    float s = v.x * v.x + v.y * v.y;
    #pragma unroll
    for (int off = 32; off > 0; off >>= 1) s += __shfl_xor(s, off);
    float r = 1.0f / sqrtf(s);
    float a0 = v.x * r, a1 = v.y * r;
    ushort h0 = f2bf(a0), h1 = f2bf(a1);
    ushort l0 = f2bf(a0 - bf2f(h0)), l1 = f2bf(a1 - bf2f(h1));
    ushort2 hv; hv.x = h0; hv.y = h1;
    ushort2 lv; lv.x = l0; lv.y = l1;
    reinterpret_cast<ushort2*>(dn_hi + (size_t)row * DIM)[lane] = hv;
    reinterpret_cast<ushort2*>(dn_lo + (size_t)row * DIM)[lane] = lv;
}

// ---------------- build K = 10*dot - 10 (diag -10000), MFMA split-bf16 ----------------
template <typename OUT>
__launch_bounds__(256, 2)
__global__ void buildK_mfma(const ushort* __restrict__ Ahi, const ushort* __restrict__ Alo,
                            OUT* __restrict__ K) {
    int tid = threadIdx.x;
    int w = tid >> 6, l = tid & 63;
    int wm = w >> 1, wn = w & 1;
    int row0 = blockIdx.y * 128 + wm * 64;
    int col0 = blockIdx.x * 128 + wn * 64;
    int lr = l & 15;
    int lk = (l >> 4) * 8;

    f32x4 acc[4][4] = {};
    #pragma unroll
    for (int ks = 0; ks < 4; ++ks) {
        int kb = ks * 32 + lk;
        bf16x8 ah[4], al[4], bh[4], bl[4];
        #pragma unroll
        for (int f = 0; f < 4; ++f) {
            size_t aoff = (size_t)(row0 + f * 16 + lr) * DIM + kb;
            size_t boff = (size_t)(col0 + f * 16 + lr) * DIM + kb;
            ah[f] = *reinterpret_cast<const bf16x8*>(Ahi + aoff);
            al[f] = *reinterpret_cast<const bf16x8*>(Alo + aoff);
            bh[f] = *reinterpret_cast<const bf16x8*>(Ahi + boff);
            bl[f] = *reinterpret_cast<const bf16x8*>(Alo + boff);
        }
        #pragma unroll
        for (int i = 0; i < 4; ++i)
            #pragma unroll
            for (int j = 0; j < 4; ++j) {
                acc[i][j] = __builtin_amdgcn_mfma_f32_16x16x32_bf16(al[i], bh[j], acc[i][j], 0, 0, 0);
                acc[i][j] = __builtin_amdgcn_mfma_f32_16x16x32_bf16(ah[i], bl[j], acc[i][j], 0, 0, 0);
                acc[i][j] = __builtin_amdgcn_mfma_f32_16x16x32_bf16(ah[i], bh[j], acc[i][j], 0, 0, 0);
            }
    }

    int orow = (l >> 4) * 4;
    #pragma unroll
    for (int i = 0; i < 4; ++i)
        #pragma unroll
        for (int j = 0; j < 4; ++j)
            #pragma unroll
            for (int r = 0; r < 4; ++r) {
                int gr = row0 + i * 16 + orow + r;
                int gc = col0 + j * 16 + lr;
                float kv = 10.0f * acc[i][j][r] - 10.0f;
                if (gr == gc) kv = -10000.0f;
                K[(size_t)gr * NROW + gc] = (OUT)kv;
            }
}

// ---------------- fused Sinkhorn iteration ----------------
// Block s owns rows [16s, 16s+16).
// Phase 1: u'_i = -log(sum_j exp(K_ij + vin_j)) for its rows (writes uout).
// Phase 2: psum[s][j] = sum_{i in stripe} exp(K_ij + u'_i)  (+ optional col max of K_ij + u'_i).
template <bool TRACK_MAX>
__launch_bounds__(256)
__global__ void sink_fused(const _Float16* __restrict__ K, const float* __restrict__ vin,
                           float* __restrict__ uout, float* __restrict__ psum,
                           float* __restrict__ pmax) {
    int s = blockIdx.x;
    int t = threadIdx.x;
    int row0 = s * RSTRIPE;
    __shared__ float ulds[RSTRIPE];

    // ---- phase 1 ----
    {
        int r  = t >> 4;    // 0..15 row within stripe
        int cg = t & 15;    // col group
        const half8* Krow = reinterpret_cast<const half8*>(K + (size_t)(row0 + r) * NROW);
        const float4* V4  = reinterpret_cast<const float4*>(vin);
        float ssum = 0.0f;
        #pragma unroll 4
        for (int stp = 0; stp < 64; ++stp) {
            int j8 = cg + stp * 16;
            half8 kk = Krow[j8];
            float4 v0 = V4[j8 * 2];
            float4 v1 = V4[j8 * 2 + 1];
            ssum += __expf((float)kk[0] + v0.x) + __expf((float)kk[1] + v0.y)
                  + __expf((float)kk[2] + v0.z) + __expf((float)kk[3] + v0.w)
                  + __expf((float)kk[4] + v1.x) + __expf((float)kk[5] + v1.y)
                  + __expf((float)kk[6] + v1.z) + __expf((float)kk[7] + v1.w);
        }
        #pragma unroll
        for (int off = 8; off > 0; off >>= 1) ssum += __shfl_xor(ssum, off);
        if (cg == 0) ulds[r] = -__logf(ssum);
    }
    __syncthreads();
    if (t < RSTRIPE) uout[row0 + t] = ulds[t];

    // ---- phase 2 ----
    float cs[32];
    float cm[32];
    #pragma unroll
    for (int q = 0; q < 32; ++q) { cs[q] = 0.0f; cm[q] = -3.4e38f; }

    #pragma unroll 1
    for (int i = 0; i < RSTRIPE; ++i) {
        float ui = ulds[i];
        const half2v* Kr2 = reinterpret_cast<const half2v*>(K + (size_t)(row0 + i) * NROW);
        #pragma unroll
        for (int k = 0; k < 16; ++k) {
            half2v kk = Kr2[t + 256 * k];
            float x0 = (float)kk[0] + ui;
            float x1 = (float)kk[1] + ui;
            cs[2 * k]     += __expf(x0);
            cs[2 * k + 1] += __expf(x1);
            if (TRACK_MAX) {
                cm[2 * k]     = fmaxf(cm[2 * k], x0);
                cm[2 * k + 1] = fmaxf(cm[2 * k + 1], x1);
            }
        }
    }
    float2* PS = reinterpret_cast<float2*>(psum + (size_t)s * NROW);
    #pragma unroll
    for (int k = 0; k < 16; ++k) {
        float2 o; o.x = cs[2 * k]; o.y = cs[2 * k + 1];
        PS[t + 256 * k] = o;
    }
    if (TRACK_MAX) {
        float2* PM = reinterpret_cast<float2*>(pmax + (size_t)s * NROW);
        #pragma unroll
        for (int k = 0; k < 16; ++k) {
            float2 o; o.x = cm[2 * k]; o.y = cm[2 * k + 1];
            PM[t + 256 * k] = o;
        }
    }
}

// ---------------- reduce: v_j = -log(sum_s psum[s][j]); optional global-max partials --------
template <bool TRACK_MAX>
__launch_bounds__(256)
__global__ void sink_reduce(const float* __restrict__ psum, const float* __restrict__ pmax,
                            float* __restrict__ vout, float* __restrict__ gpart) {
    __shared__ float lsum[8][32];
    __shared__ float lmax[8][32];
    int b = blockIdx.x;         // 256 blocks, 32 cols each
    int t = threadIdx.x;
    int jc = t & 31;
    int sg = t >> 5;            // 0..7
    int j = b * 32 + jc;
    float ssum = 0.0f, mm = -3.4e38f;
    for (int s = sg; s < NSTRIPE; s += 8) {
        ssum += psum[(size_t)s * NROW + j];
        if (TRACK_MAX) mm = fmaxf(mm, pmax[(size_t)s * NROW + j]);
    }
    lsum[sg][jc] = ssum;
    if (TRACK_MAX) lmax[sg][jc] = mm;
    __syncthreads();
    if (t < 32) {
        float S = 0.0f, M = -3.4e38f;
        #pragma unroll
        for (int g = 0; g < 8; ++g) {
            S += lsum[g][t];
            if (TRACK_MAX) M = fmaxf(M, lmax[g][t]);
        }
        float vj = -__logf(S);
        vout[b * 32 + t] = vj;
        if (TRACK_MAX) {
            M += vj;
            #pragma unroll
            for (int off = 16; off > 0; off >>= 1) M = fmaxf(M, __shfl_xor(M, off));
            if (t == 0) gpart[b] = M;
        }
    }
}

// ---------------- sc = 1/sigmoid(global max) ----------------
__global__ void sc_kernel(const float* __restrict__ gpart, float* __restrict__ sc) {
    int t = threadIdx.x;   // 256
    float m = gpart[t];
    #pragma unroll
    for (int off = 32; off > 0; off >>= 1) m = fmaxf(m, __shfl_xor(m, off));
    __shared__ float lm[4];
    if ((t & 63) == 0) lm[t >> 6] = m;
    __syncthreads();
    if (t == 0) {
        float M = fmaxf(fmaxf(lm[0], lm[1]), fmaxf(lm[2], lm[3]));
        sc[0] = 1.0f + __expf(-M);
    }
}

// ---------------- finalize (fp16 K -> fp32 out) ----------------
__launch_bounds__(256)
__global__ void finalize16_kernel(const _Float16* __restrict__ K, float* __restrict__ out,
                                  const float* __restrict__ u, const float* __restrict__ v,
                                  const float* __restrict__ sc) {
    float s_inv = sc[0];
    const size_t nt8 = (size_t)NROW * NROW / 8;
    size_t stride = (size_t)gridDim.x * blockDim.x;
    for (size_t e = (size_t)blockIdx.x * blockDim.x + threadIdx.x; e < nt8; e += stride) {
        size_t i = e >> 10;
        int j0 = (int)((e & 1023) << 3);
        half8 kk = reinterpret_cast<const half8*>(K)[e];
        float4 v0 = reinterpret_cast<const float4*>(v)[(e & 1023) * 2];
        float4 v1 = reinterpret_cast<const float4*>(v)[(e & 1023) * 2 + 1];
        float ui = u[i];
        float x[8];
        x[0] = ui + (float)kk[0] + v0.x; x[1] = ui + (float)kk[1] + v0.y;
        x[2] = ui + (float)kk[2] + v0.z; x[3] = ui + (float)kk[3] + v0.w;
        x[4] = ui + (float)kk[4] + v1.x; x[5] = ui + (float)kk[5] + v1.y;
        x[6] = ui + (float)kk[6] + v1.z; x[7] = ui + (float)kk[7] + v1.w;
        float o[8];
        #pragma unroll
        for (int tt = 0; tt < 8; ++tt)
            o[tt] = s_inv * __builtin_amdgcn_rcpf(1.0f + __expf(-x[tt]));
        if (i >= (size_t)j0 && i < (size_t)j0 + 8) o[i - j0] = 1.0f;
        float4 oa; oa.x = o[0]; oa.y = o[1]; oa.z = o[2]; oa.w = o[3];
        float4 ob; ob.x = o[4]; ob.y = o[5]; ob.z = o[6]; ob.w = o[7];
        reinterpret_cast<float4*>(out)[e * 2] = oa;
        reinterpret_cast<float4*>(out)[e * 2 + 1] = ob;
    }
}

// ======== fallback fp32 path kernels (small workspace) ========
__launch_bounds__(256)
__global__ void lse_kernel(const float* __restrict__ K, const float* __restrict__ vin,
                           float* __restrict__ out, float* __restrict__ rmax) {
    int row = blockIdx.x;
    int tid = threadIdx.x;
    const float4* Krow = reinterpret_cast<const float4*>(K + (size_t)row * NROW);
    const float4* V4 = reinterpret_cast<const float4*>(vin);
    float s = 0.0f;
    float m = -3.4e38f;
    #pragma unroll
    for (int w = 0; w < 8; ++w) {
        int j4 = tid + w * 256;
        float4 kk = Krow[j4];
        float4 vv = V4[j4];
        float x0 = kk.x + vv.x, x1 = kk.y + vv.y, x2 = kk.z + vv.z, x3 = kk.w + vv.w;
        s += __expf(x0) + __expf(x1) + __expf(x2) + __expf(x3);
        m = fmaxf(m, fmaxf(fmaxf(x0, x1), fmaxf(x2, x3)));
    }
    #pragma unroll
    for (int off = 32; off > 0; off >>= 1) {
        s += __shfl_xor(s, off);
        m = fmaxf(m, __shfl_xor(m, off));
    }
    __shared__ float ls[4], lm[4];
    int wid = tid >> 6;
    if ((tid & 63) == 0) { ls[wid] = s; lm[wid] = m; }
    __syncthreads();
    if (tid == 0) {
        out[row] = -__logf(ls[0] + ls[1] + ls[2] + ls[3]);
        rmax[row] = fmaxf(fmaxf(lm[0], lm[1]), fmaxf(lm[2], lm[3]));
    }
}

__global__ void maxred_kernel(const float* __restrict__ v, const float* __restrict__ rmax,
                              float* __restrict__ sc) {
    int tid = threadIdx.x;
    float m = -3.4e38f;
    for (int j = tid; j < NROW; j += 256) m = fmaxf(m, v[j] + rmax[j]);
    #pragma unroll
    for (int off = 32; off > 0; off >>= 1) m = fmaxf(m, __shfl_xor(m, off));
    __shared__ float lm[4];
    if ((tid & 63) == 0) lm[tid >> 6] = m;
    __syncthreads();
    if (tid == 0) {
        float M = fmaxf(fmaxf(lm[0], lm[1]), fmaxf(lm[2], lm[3]));
        sc[0] = 1.0f + __expf(-M);
    }
}

__launch_bounds__(256)
__global__ void finalize_kernel(float* __restrict__ K, const float* __restrict__ u,
                                const float* __restrict__ v, const float* __restrict__ sc) {
    float s_inv = sc[0];
    const size_t nt4 = (size_t)NROW * NROW / 4;
    size_t stride = (size_t)gridDim.x * blockDim.x;
    for (size_t e = (size_t)blockIdx.x * blockDim.x + threadIdx.x; e < nt4; e += stride) {
        size_t i = e >> 11;
        int j0 = (int)((e & 2047) << 2);
        float4 kk = reinterpret_cast<const float4*>(K)[e];
        float4 vv = reinterpret_cast<const float4*>(v)[e & 2047];
        float ui = u[i];
        float x[4] = { ui + kk.x + vv.x, ui + kk.y + vv.y, ui + kk.z + vv.z, ui + kk.w + vv.w };
        float o[4];
        #pragma unroll
        for (int tt = 0; tt < 4; ++tt)
            o[tt] = s_inv * __builtin_amdgcn_rcpf(1.0f + __expf(-x[tt]));
        if (i >= (size_t)j0 && i < (size_t)j0 + 4) o[i - j0] = 1.0f;
        float4 ov; ov.x = o[0]; ov.y = o[1]; ov.z = o[2]; ov.w = o[3];
        reinterpret_cast<float4*>(K)[e] = ov;
    }
}

extern "C" void kernel_launch(void* const* d_in, const int* in_sizes, int n_in,
                              void* d_out, int out_size, void* d_ws, size_t ws_size,
                              hipStream_t stream) {
    const float* X = (const float*)d_in[0];
    float* out = (float*)d_out;
    char* ws = (char*)d_ws;

    size_t off = 0;
    ushort* dn_hi = (ushort*)(ws + off); off += (size_t)NROW * DIM * 2;
    ushort* dn_lo = (ushort*)(ws + off); off += (size_t)NROW * DIM * 2;
    float* u    = (float*)(ws + off); off += NROW * 4;
    float* v    = (float*)(ws + off); off += NROW * 4;
    float* rmax = (float*)(ws + off); off += NROW * 4;
    float* sc   = (float*)(ws + off); off += 256;
    float* gpart = (float*)(ws + off); off += 256 * 4;
    off = (off + 255) & ~(size_t)255;
    _Float16* K16 = (_Float16*)(ws + off); off += (size_t)NROW * NROW * 2;   // 128 MiB
    float* psum = (float*)(ws + off); off += (size_t)NSTRIPE * NROW * 4;     // 16 MiB
    float* pmax = (float*)(ws + off); off += (size_t)NSTRIPE * NROW * 4;     // 16 MiB
    size_t need16 = off;

    hipMemsetAsync(v, 0, NROW * sizeof(float), stream);
    rownorm_kernel<<<NROW, 64, 0, stream>>>(X, dn_hi, dn_lo);

    dim3 g(NROW / 128, NROW / 128);
    if (ws_size >= need16) {
        buildK_mfma<_Float16><<<g, 256, 0, stream>>>(dn_hi, dn_lo, K16);
        for (int it = 0; it < 10; ++it) {
            if (it == 9) {
                sink_fused<true><<<NSTRIPE, 256, 0, stream>>>(K16, v, u, psum, pmax);
                sink_reduce<true><<<NROW / 32, 256, 0, stream>>>(psum, pmax, v, gpart);
            } else {
                sink_fused<false><<<NSTRIPE, 256, 0, stream>>>(K16, v, u, psum, pmax);
                sink_reduce<false><<<NROW / 32, 256, 0, stream>>>(psum, pmax, v, gpart);
            }
        }
        sc_kernel<<<1, 256, 0, stream>>>(gpart, sc);
        finalize16_kernel<<<4096, 256, 0, stream>>>(K16, out, u, v, sc);
    } else {
        buildK_mfma<float><<<g, 256, 0, stream>>>(dn_hi, dn_lo, out);
        for (int it = 0; it < 10; ++it) {
            lse_kernel<<<NROW, 256, 0, stream>>>(out, v, u, rmax);
            lse_kernel<<<NROW, 256, 0, stream>>>(out, u, v, rmax);
        }
        maxred_kernel<<<1, 256, 0, stream>>>(v, rmax, sc);
        finalize_kernel<<<4096, 256, 0, stream>>>(out, u, v, sc);
    }
}

// Round 4
// 780.359 us; speedup vs baseline: 1.0935x; 1.0935x over previous
//
#include <hip/hip_runtime.h>
#include <hip/hip_bf16.h>
#include <hip/hip_fp16.h>
#include <math.h>

#define NROW 8192
#define DIM  128
#define ESCALE 8192.0f

typedef short bf16x8 __attribute__((ext_vector_type(8)));
typedef float f32x4  __attribute__((ext_vector_type(4)));
typedef _Float16 half8 __attribute__((ext_vector_type(8)));

__device__ inline ushort f2bf(float x) { __hip_bfloat16 b = __float2bfloat16(x); return *(ushort*)&b; }
__device__ inline float  bf2f(ushort u) { __hip_bfloat16 b; *(ushort*)&b = u; return __bfloat162float(b); }

// ---------------- init: b=1, y0=y1=0, cmax=0, gpm=0 ----------------
__global__ void init_kernel(float* __restrict__ b, float* __restrict__ y0,
                            float* __restrict__ y1, unsigned* __restrict__ cmax,
                            unsigned* __restrict__ gpm) {
    int i = blockIdx.x * 256 + threadIdx.x;
    b[i] = 1.0f;
    y0[i] = 0.0f;
    y1[i] = 0.0f;
    cmax[i] = 0u;
    if (i == 0) gpm[0] = 0u;
}

// ---------------- row normalize + split into bf16 hi/lo ----------------
__global__ void rownorm_kernel(const float* __restrict__ X,
                               ushort* __restrict__ dn_hi, ushort* __restrict__ dn_lo) {
    int row = blockIdx.x;
    int lane = threadIdx.x;            // 64 lanes
    const float2* x2 = reinterpret_cast<const float2*>(X + (size_t)row * DIM);
    float2 v = x2[lane];
    float s = v.x * v.x + v.y * v.y;
    #pragma unroll
    for (int off = 32; off > 0; off >>= 1) s += __shfl_xor(s, off);
    float r = 1.0f / sqrtf(s);
    float a0 = v.x * r, a1 = v.y * r;
    ushort h0 = f2bf(a0), h1 = f2bf(a1);
    ushort l0 = f2bf(a0 - bf2f(h0)), l1 = f2bf(a1 - bf2f(h1));
    ushort2 hv; hv.x = h0; hv.y = h1;
    ushort2 lv; lv.x = l0; lv.y = l1;
    reinterpret_cast<ushort2*>(dn_hi + (size_t)row * DIM)[lane] = hv;
    reinterpret_cast<ushort2*>(dn_lo + (size_t)row * DIM)[lane] = lv;
}

// ---------------- build E' = ESCALE * exp(10*dot - 10), diag 0, MFMA split-bf16 --------
__launch_bounds__(256, 2)
__global__ void buildE_mfma(const ushort* __restrict__ Ahi, const ushort* __restrict__ Alo,
                            _Float16* __restrict__ E) {
    int tid = threadIdx.x;
    int w = tid >> 6, l = tid & 63;
    int wm = w >> 1, wn = w & 1;
    int row0 = blockIdx.y * 128 + wm * 64;
    int col0 = blockIdx.x * 128 + wn * 64;
    int lr = l & 15;
    int lk = (l >> 4) * 8;

    f32x4 acc[4][4] = {};
    #pragma unroll
    for (int ks = 0; ks < 4; ++ks) {
        int kb = ks * 32 + lk;
        bf16x8 ah[4], al[4], bh[4], bl[4];
        #pragma unroll
        for (int f = 0; f < 4; ++f) {
            size_t aoff = (size_t)(row0 + f * 16 + lr) * DIM + kb;
            size_t boff = (size_t)(col0 + f * 16 + lr) * DIM + kb;
            ah[f] = *reinterpret_cast<const bf16x8*>(Ahi + aoff);
            al[f] = *reinterpret_cast<const bf16x8*>(Alo + aoff);
            bh[f] = *reinterpret_cast<const bf16x8*>(Ahi + boff);
            bl[f] = *reinterpret_cast<const bf16x8*>(Alo + boff);
        }
        #pragma unroll
        for (int i = 0; i < 4; ++i)
            #pragma unroll
            for (int j = 0; j < 4; ++j) {
                acc[i][j] = __builtin_amdgcn_mfma_f32_16x16x32_bf16(al[i], bh[j], acc[i][j], 0, 0, 0);
                acc[i][j] = __builtin_amdgcn_mfma_f32_16x16x32_bf16(ah[i], bl[j], acc[i][j], 0, 0, 0);
                acc[i][j] = __builtin_amdgcn_mfma_f32_16x16x32_bf16(ah[i], bh[j], acc[i][j], 0, 0, 0);
            }
    }

    int orow = (l >> 4) * 4;
    #pragma unroll
    for (int i = 0; i < 4; ++i)
        #pragma unroll
        for (int j = 0; j < 4; ++j)
            #pragma unroll
            for (int r = 0; r < 4; ++r) {
                int gr = row0 + i * 16 + orow + r;
                int gc = col0 + j * 16 + lr;
                float kv = 10.0f * acc[i][j][r] - 10.0f;
                float ev = (gr == gc) ? 0.0f : __expf(kv) * ESCALE;
                E[(size_t)gr * NROW + gc] = (_Float16)ev;
            }
}

// ---------------- symmetric matvec over upper-triangle blocks ----------------
// y += E x using only tiles (bi,bj) with bj>=bi; off-diag tiles contribute to
// y[I] (row pass with x[J]) and y[J] (mirror col pass with x[I]).
// TRACK_MAX: cmax[c] = max over full matrix of E[r][c]*x[r] (as uint bits, all >=0).
template <bool TRACK_MAX>
__launch_bounds__(256)
__global__ void symv_kernel(const _Float16* __restrict__ E, const float* __restrict__ x,
                            float* __restrict__ y, unsigned* __restrict__ cmax) {
    int bi = blockIdx.y, bj = blockIdx.x;
    if (bj < bi) return;
    const bool diag = (bi == bj);
    const int I0 = bi * 128, J0 = bj * 128;
    int t = threadIdx.x;
    int g = t & 15;        // 8-col group
    int r = t >> 4;        // row subgroup 0..15

    float xj[8];
    {
        float4 t0 = *reinterpret_cast<const float4*>(x + J0 + 8 * g);
        float4 t1 = *reinterpret_cast<const float4*>(x + J0 + 8 * g + 4);
        xj[0] = t0.x; xj[1] = t0.y; xj[2] = t0.z; xj[3] = t0.w;
        xj[4] = t1.x; xj[5] = t1.y; xj[6] = t1.z; xj[7] = t1.w;
    }
    float xi[8];
    if (!diag) {
        #pragma unroll
        for (int s = 0; s < 8; ++s) xi[s] = x[I0 + r + 16 * s];
    }
    float ca[8] = {0, 0, 0, 0, 0, 0, 0, 0};
    float cmx[8] = {0, 0, 0, 0, 0, 0, 0, 0};

    #pragma unroll
    for (int s = 0; s < 8; ++s) {
        int row = r + 16 * s;
        half8 e = *reinterpret_cast<const half8*>(E + (size_t)(I0 + row) * NROW + J0 + 8 * g);
        float ef[8];
        #pragma unroll
        for (int k = 0; k < 8; ++k) ef[k] = (float)e[k];
        float rs = 0.0f, rm = 0.0f;
        #pragma unroll
        for (int k = 0; k < 8; ++k) {
            float p = ef[k] * xj[k];
            rs += p;
            if (TRACK_MAX) rm = fmaxf(rm, p);
        }
        #pragma unroll
        for (int off = 1; off <= 8; off <<= 1) {
            rs += __shfl_xor(rs, off);
            if (TRACK_MAX) rm = fmaxf(rm, __shfl_xor(rm, off));
        }
        if (g == 0) {
            atomicAdd(&y[I0 + row], rs);
            if (TRACK_MAX) atomicMax(&cmax[I0 + row], __float_as_uint(rm));
        }
        if (!diag) {
            #pragma unroll
            for (int k = 0; k < 8; ++k) {
                float p = ef[k] * xi[s];
                ca[k] += p;
                if (TRACK_MAX) cmx[k] = fmaxf(cmx[k], p);
            }
        }
    }

    __shared__ float lsum[4][16][8];
    __shared__ float lmax[4][16][8];
    if (!diag) {
        #pragma unroll
        for (int k = 0; k < 8; ++k) {
            ca[k] += __shfl_xor(ca[k], 16);
            ca[k] += __shfl_xor(ca[k], 32);
            if (TRACK_MAX) {
                cmx[k] = fmaxf(cmx[k], __shfl_xor(cmx[k], 16));
                cmx[k] = fmaxf(cmx[k], __shfl_xor(cmx[k], 32));
            }
        }
        int w = t >> 6;
        if ((t & 48) == 0) {
            #pragma unroll
            for (int k = 0; k < 8; ++k) {
                lsum[w][g][k] = ca[k];
                if (TRACK_MAX) lmax[w][g][k] = cmx[k];
            }
        }
        __syncthreads();
        if (t < 128) {
            int gg = t >> 3, kk = t & 7;
            float S = lsum[0][gg][kk] + lsum[1][gg][kk] + lsum[2][gg][kk] + lsum[3][gg][kk];
            atomicAdd(&y[J0 + 8 * gg + kk], S);
            if (TRACK_MAX) {
                float M = fmaxf(fmaxf(lmax[0][gg][kk], lmax[1][gg][kk]),
                                fmaxf(lmax[2][gg][kk], lmax[3][gg][kk]));
                atomicMax(&cmax[J0 + 8 * gg + kk], __float_as_uint(M));
            }
        }
    }
}

// ---------------- recip: xout = 1/y, then zero y for its next use ----------------
__global__ void recip_kernel(float* __restrict__ y, float* __restrict__ xout) {
    int i = blockIdx.x * 256 + threadIdx.x;
    float yv = y[i];
    xout[i] = 1.0f / yv;
    y[i] = 0.0f;
}

// ---------------- final recip + Pm partial: gpm = max(cmax[j] * b[j]) ----------------
__global__ void recip_pm_kernel(float* __restrict__ y, float* __restrict__ xout,
                                const unsigned* __restrict__ cmax, unsigned* __restrict__ gpm) {
    int i = blockIdx.x * 256 + threadIdx.x;
    float yv = y[i];
    float b = 1.0f / yv;
    xout[i] = b;
    y[i] = 0.0f;
    float pv = __uint_as_float(cmax[i]) * b;
    #pragma unroll
    for (int off = 32; off > 0; off >>= 1) pv = fmaxf(pv, __shfl_xor(pv, off));
    __shared__ float lm[4];
    int t = threadIdx.x;
    if ((t & 63) == 0) lm[t >> 6] = pv;
    __syncthreads();
    if (t == 0) {
        float M = fmaxf(fmaxf(lm[0], lm[1]), fmaxf(lm[2], lm[3]));
        atomicMax(gpm, __float_as_uint(M));
    }
}

// ---------------- sc: scp = (1+Pm)/Pm ----------------
__global__ void sc_kernel(const unsigned* __restrict__ gpm, float* __restrict__ scp) {
    float Pm = __uint_as_float(gpm[0]);
    scp[0] = (1.0f + Pm) / Pm;
}

// ---------------- finalize: out = S * P/(1+P), P = a_i E_ij b_j, diag = 1 --------
__launch_bounds__(256)
__global__ void finalize_mult(const _Float16* __restrict__ E, float* __restrict__ out,
                              const float* __restrict__ a, const float* __restrict__ b,
                              const float* __restrict__ scp) {
    float S = scp[0];
    const size_t nt8 = (size_t)NROW * NROW / 8;
    size_t stride = (size_t)gridDim.x * blockDim.x;
    for (size_t e8 = (size_t)blockIdx.x * blockDim.x + threadIdx.x; e8 < nt8; e8 += stride) {
        size_t i = e8 >> 10;                 // 1024 half8 per row
        int j0 = (int)((e8 & 1023) << 3);
        half8 ev = reinterpret_cast<const half8*>(E)[e8];
        float4 b0 = reinterpret_cast<const float4*>(b)[(e8 & 1023) * 2];
        float4 b1 = reinterpret_cast<const float4*>(b)[(e8 & 1023) * 2 + 1];
        float ai = a[i];
        float P[8];
        P[0] = ai * (float)ev[0] * b0.x; P[1] = ai * (float)ev[1] * b0.y;
        P[2] = ai * (float)ev[2] * b0.z; P[3] = ai * (float)ev[3] * b0.w;
        P[4] = ai * (float)ev[4] * b1.x; P[5] = ai * (float)ev[5] * b1.y;
        P[6] = ai * (float)ev[6] * b1.z; P[7] = ai * (float)ev[7] * b1.w;
        float o[8];
        #pragma unroll
        for (int tt = 0; tt < 8; ++tt)
            o[tt] = S * P[tt] * __builtin_amdgcn_rcpf(1.0f + P[tt]);
        if (i >= (size_t)j0 && i < (size_t)j0 + 8) o[i - j0] = 1.0f;
        float4 oa; oa.x = o[0]; oa.y = o[1]; oa.z = o[2]; oa.w = o[3];
        float4 ob; ob.x = o[4]; ob.y = o[5]; ob.z = o[6]; ob.w = o[7];
        reinterpret_cast<float4*>(out)[e8 * 2] = oa;
        reinterpret_cast<float4*>(out)[e8 * 2 + 1] = ob;
    }
}

extern "C" void kernel_launch(void* const* d_in, const int* in_sizes, int n_in,
                              void* d_out, int out_size, void* d_ws, size_t ws_size,
                              hipStream_t stream) {
    const float* X = (const float*)d_in[0];
    float* out = (float*)d_out;
    char* ws = (char*)d_ws;

    size_t off = 0;
    ushort* dn_hi = (ushort*)(ws + off); off += (size_t)NROW * DIM * 2;   // 2 MB
    ushort* dn_lo = (ushort*)(ws + off); off += (size_t)NROW * DIM * 2;   // 2 MB
    float* avec  = (float*)(ws + off); off += NROW * 4;
    float* bvec  = (float*)(ws + off); off += NROW * 4;
    float* y0    = (float*)(ws + off); off += NROW * 4;
    float* y1    = (float*)(ws + off); off += NROW * 4;
    unsigned* cmax = (unsigned*)(ws + off); off += NROW * 4;
    unsigned* gpm  = (unsigned*)(ws + off); off += 64;
    float* scp   = (float*)(ws + off); off += 64;
    off = (off + 255) & ~(size_t)255;
    _Float16* E = (_Float16*)(ws + off); off += (size_t)NROW * NROW * 2;  // 128 MiB

    init_kernel<<<NROW / 256, 256, 0, stream>>>(bvec, y0, y1, cmax, gpm);
    rownorm_kernel<<<NROW, 64, 0, stream>>>(X, dn_hi, dn_lo);

    dim3 g(NROW / 128, NROW / 128);
    buildE_mfma<<<g, 256, 0, stream>>>(dn_hi, dn_lo, E);

    for (int it = 0; it < 10; ++it) {
        bool last = (it == 9);
        symv_kernel<false><<<g, 256, 0, stream>>>(E, bvec, y0, cmax);
        recip_kernel<<<NROW / 256, 256, 0, stream>>>(y0, avec);
        if (!last) {
            symv_kernel<false><<<g, 256, 0, stream>>>(E, avec, y1, cmax);
            recip_kernel<<<NROW / 256, 256, 0, stream>>>(y1, bvec);
        } else {
            symv_kernel<true><<<g, 256, 0, stream>>>(E, avec, y1, cmax);
            recip_pm_kernel<<<NROW / 256, 256, 0, stream>>>(y1, bvec, cmax, gpm);
        }
    }

    sc_kernel<<<1, 1, 0, stream>>>(gpm, scp);
    finalize_mult<<<4096, 256, 0, stream>>>(E, out, avec, bvec, scp);
}

// Round 5
// 543.587 us; speedup vs baseline: 1.5698x; 1.4356x over previous
//
#include <hip/hip_runtime.h>
#include <hip/hip_bf16.h>
#include <hip/hip_fp16.h>
#include <math.h>

#define NROW 8192
#define DIM  128
#define ESCALE 8192.0f
#define NPASS 20            // total E-applications; pass 0 fused into buildE
#define SH 64               // stripe height (rows per unit)
#define CW 256              // unit column width
#define NUNITS 2112         // sum over stripes of ceil((NROW - 64s)/256) aligned to 256q

typedef short bf16x8 __attribute__((ext_vector_type(8)));
typedef float f32x4  __attribute__((ext_vector_type(4)));
typedef _Float16 half8 __attribute__((ext_vector_type(8)));

__device__ inline ushort f2bf(float x) { __hip_bfloat16 b = __float2bfloat16(x); return *(ushort*)&b; }
__device__ inline float  bf2f(ushort u) { __hip_bfloat16 b; *(ushort*)&b = u; return __bfloat162float(b); }

// ---------------- init: zero the y-buffer chain, cmax, gpm ----------------
__global__ void init_kernel(float* __restrict__ ybuf, unsigned* __restrict__ cmax,
                            unsigned* __restrict__ gpm) {
    int i = blockIdx.x * 256 + threadIdx.x;     // grid sized exactly NPASS*NROW
    ybuf[i] = 0.0f;
    if (i < NROW) cmax[i] = 0u;
    if (i == 0) gpm[0] = 0u;
}

// ---------------- row normalize + split into bf16 hi/lo ----------------
__global__ void rownorm_kernel(const float* __restrict__ X,
                               ushort* __restrict__ dn_hi, ushort* __restrict__ dn_lo) {
    int row = blockIdx.x;
    int lane = threadIdx.x;            // 64 lanes
    const float2* x2 = reinterpret_cast<const float2*>(X + (size_t)row * DIM);
    float2 v = x2[lane];
    float s = v.x * v.x + v.y * v.y;
    #pragma unroll
    for (int off = 32; off > 0; off >>= 1) s += __shfl_xor(s, off);
    float r = 1.0f / sqrtf(s);
    float a0 = v.x * r, a1 = v.y * r;
    ushort h0 = f2bf(a0), h1 = f2bf(a1);
    ushort l0 = f2bf(a0 - bf2f(h0)), l1 = f2bf(a1 - bf2f(h1));
    ushort2 hv; hv.x = h0; hv.y = h1;
    ushort2 lv; lv.x = l0; lv.y = l1;
    reinterpret_cast<ushort2*>(dn_hi + (size_t)row * DIM)[lane] = hv;
    reinterpret_cast<ushort2*>(dn_lo + (size_t)row * DIM)[lane] = lv;
}

// ------- build E = ESCALE*exp(10*dot-10), diag 0; fused pass-0 row sums -> y0 -------
__launch_bounds__(256, 2)
__global__ void buildE_mfma(const ushort* __restrict__ Ahi, const ushort* __restrict__ Alo,
                            _Float16* __restrict__ E, float* __restrict__ y0) {
    int tid = threadIdx.x;
    int w = tid >> 6, l = tid & 63;
    int wm = w >> 1, wn = w & 1;
    int row0 = blockIdx.y * 128 + wm * 64;
    int col0 = blockIdx.x * 128 + wn * 64;
    int lr = l & 15;
    int lk = (l >> 4) * 8;

    f32x4 acc[4][4] = {};
    #pragma unroll
    for (int ks = 0; ks < 4; ++ks) {
        int kb = ks * 32 + lk;
        bf16x8 ah[4], al[4], bh[4], bl[4];
        #pragma unroll
        for (int f = 0; f < 4; ++f) {
            size_t aoff = (size_t)(row0 + f * 16 + lr) * DIM + kb;
            size_t boff = (size_t)(col0 + f * 16 + lr) * DIM + kb;
            ah[f] = *reinterpret_cast<const bf16x8*>(Ahi + aoff);
            al[f] = *reinterpret_cast<const bf16x8*>(Alo + aoff);
            bh[f] = *reinterpret_cast<const bf16x8*>(Ahi + boff);
            bl[f] = *reinterpret_cast<const bf16x8*>(Alo + boff);
        }
        #pragma unroll
        for (int i = 0; i < 4; ++i)
            #pragma unroll
            for (int j = 0; j < 4; ++j) {
                acc[i][j] = __builtin_amdgcn_mfma_f32_16x16x32_bf16(al[i], bh[j], acc[i][j], 0, 0, 0);
                acc[i][j] = __builtin_amdgcn_mfma_f32_16x16x32_bf16(ah[i], bl[j], acc[i][j], 0, 0, 0);
                acc[i][j] = __builtin_amdgcn_mfma_f32_16x16x32_bf16(ah[i], bh[j], acc[i][j], 0, 0, 0);
            }
    }

    int orow = (l >> 4) * 4;
    #pragma unroll
    for (int i = 0; i < 4; ++i) {
        #pragma unroll
        for (int r = 0; r < 4; ++r) {
            int gr = row0 + i * 16 + orow + r;
            float rsum = 0.0f;
            #pragma unroll
            for (int j = 0; j < 4; ++j) {
                int gc = col0 + j * 16 + lr;
                float kv = 10.0f * acc[i][j][r] - 10.0f;
                _Float16 eh = (gr == gc) ? (_Float16)0.0f : (_Float16)(__expf(kv) * ESCALE);
                E[(size_t)gr * NROW + gc] = eh;
                rsum += (float)eh;
            }
            #pragma unroll
            for (int off = 1; off <= 8; off <<= 1) rsum += __shfl_xor(rsum, off);
            if (lr == 0) atomicAdd(&y0[gr], rsum);
        }
    }
}

// ---------------- one Sinkhorn half-pass over upper-triangle units ----------------
// Unit = 64 rows x 256 cols; x = rcp(yprev) on the fly; ynext += E x (row side)
// and += mirror contributions (col side). TRACK: per-col max of x_i*E[i][c] -> cmax.
template <bool TRACK>
__launch_bounds__(256, 4)
__global__ void symv_tri(const _Float16* __restrict__ E, const float* __restrict__ yprev,
                         float* __restrict__ ynext, unsigned* __restrict__ cmax) {
    __shared__ float lds[2048];   // 8 KB, reused across phases
    // ---- unit -> (stripe s, col chunk) ----
    int bid = blockIdx.x;
    int q = 0, cum = 0;
    while (bid >= cum + 4 * (32 - q)) { cum += 4 * (32 - q); ++q; }
    int within = bid - cum;
    int cnt = 32 - q;
    int s = 4 * q + within / cnt;
    int c = within % cnt;
    int row0 = s * SH;
    int col0 = (q + c) * CW;

    int t = threadIdx.x;
    int cg = t & 31;       // 8-col group
    int rg = t >> 5;       // 8-row group

    float xj[8], xi[8];
    {
        float4 ya = *reinterpret_cast<const float4*>(yprev + col0 + 8 * cg);
        float4 yb = *reinterpret_cast<const float4*>(yprev + col0 + 8 * cg + 4);
        xj[0] = __builtin_amdgcn_rcpf(ya.x); xj[1] = __builtin_amdgcn_rcpf(ya.y);
        xj[2] = __builtin_amdgcn_rcpf(ya.z); xj[3] = __builtin_amdgcn_rcpf(ya.w);
        xj[4] = __builtin_amdgcn_rcpf(yb.x); xj[5] = __builtin_amdgcn_rcpf(yb.y);
        xj[6] = __builtin_amdgcn_rcpf(yb.z); xj[7] = __builtin_amdgcn_rcpf(yb.w);
        float4 yc = *reinterpret_cast<const float4*>(yprev + row0 + 8 * rg);
        float4 yd = *reinterpret_cast<const float4*>(yprev + row0 + 8 * rg + 4);
        xi[0] = __builtin_amdgcn_rcpf(yc.x); xi[1] = __builtin_amdgcn_rcpf(yc.y);
        xi[2] = __builtin_amdgcn_rcpf(yc.z); xi[3] = __builtin_amdgcn_rcpf(yc.w);
        xi[4] = __builtin_amdgcn_rcpf(yd.x); xi[5] = __builtin_amdgcn_rcpf(yd.y);
        xi[6] = __builtin_amdgcn_rcpf(yd.z); xi[7] = __builtin_amdgcn_rcpf(yd.w);
    }

    float rowacc[8] = {0, 0, 0, 0, 0, 0, 0, 0};
    float colacc[8] = {0, 0, 0, 0, 0, 0, 0, 0};
    float rowmax[8] = {0, 0, 0, 0, 0, 0, 0, 0};
    float colmax[8] = {0, 0, 0, 0, 0, 0, 0, 0};

    const _Float16* Ebase = E + (size_t)(row0 + 8 * rg) * NROW + col0 + 8 * cg;
    if (col0 >= row0 + SH) {
        // fully right of the diagonal band — no masking
        #pragma unroll
        for (int r = 0; r < 8; ++r) {
            half8 e = *reinterpret_cast<const half8*>(Ebase + (size_t)r * NROW);
            #pragma unroll
            for (int k = 0; k < 8; ++k) {
                float ef = (float)e[k];
                float pr = ef * xj[k];
                float pc = ef * xi[r];
                rowacc[r] += pr;
                colacc[k] += pc;
                if (TRACK) { rowmax[r] = fmaxf(rowmax[r], pr); colmax[k] = fmaxf(colmax[k], pc); }
            }
        }
    } else {
        int grow0 = row0 + 8 * rg;
        #pragma unroll
        for (int r = 0; r < 8; ++r) {
            half8 e = *reinterpret_cast<const half8*>(Ebase + (size_t)r * NROW);
            int grow = grow0 + r;
            #pragma unroll
            for (int k = 0; k < 8; ++k) {
                float ef = (col0 + 8 * cg + k > grow) ? (float)e[k] : 0.0f;
                float pr = ef * xj[k];
                float pc = ef * xi[r];
                rowacc[r] += pr;
                colacc[k] += pc;
                if (TRACK) { rowmax[r] = fmaxf(rowmax[r], pr); colmax[k] = fmaxf(colmax[k], pc); }
            }
        }
    }

    // ---- col sums: reduce over the 8 rg groups ----
    #pragma unroll
    for (int k = 0; k < 8; ++k) lds[rg * 256 + 8 * cg + k] = colacc[k];
    __syncthreads();
    {
        float csum = 0.0f;
        #pragma unroll
        for (int g = 0; g < 8; ++g) csum += lds[g * 256 + t];
        atomicAdd(&ynext[col0 + t], csum);
    }
    __syncthreads();
    // ---- row sums: reduce over the 32 cg groups (rotated layout: conflict-free) ----
    #pragma unroll
    for (int r = 0; r < 8; ++r) {
        int rr = 8 * rg + r;
        lds[rr * 32 + ((cg + rr) & 31)] = rowacc[r];
    }
    __syncthreads();
    if (t < 64) {
        float rsum = 0.0f;
        #pragma unroll
        for (int g = 0; g < 32; ++g) rsum += lds[t * 32 + ((g + t) & 31)];
        atomicAdd(&ynext[row0 + t], rsum);
    }

    if (TRACK) {
        __syncthreads();
        #pragma unroll
        for (int k = 0; k < 8; ++k) lds[rg * 256 + 8 * cg + k] = colmax[k];
        __syncthreads();
        {
            float cmx = 0.0f;
            #pragma unroll
            for (int g = 0; g < 8; ++g) cmx = fmaxf(cmx, lds[g * 256 + t]);
            atomicMax(&cmax[col0 + t], __float_as_uint(cmx));
        }
        __syncthreads();
        #pragma unroll
        for (int r = 0; r < 8; ++r) {
            int rr = 8 * rg + r;
            lds[rr * 32 + ((cg + rr) & 31)] = rowmax[r];
        }
        __syncthreads();
        if (t < 64) {
            float rmx = 0.0f;
            #pragma unroll
            for (int g = 0; g < 32; ++g) rmx = fmaxf(rmx, lds[t * 32 + ((g + t) & 31)]);
            atomicMax(&cmax[row0 + t], __float_as_uint(rmx));
        }
    }
}

// ---------------- a=1/y18, b=1/y19, Pm partials -> gpm ----------------
__global__ void vecfinish(const float* __restrict__ y18, const float* __restrict__ y19,
                          const unsigned* __restrict__ cmax, float* __restrict__ avec,
                          float* __restrict__ bvec, unsigned* __restrict__ gpm) {
    int i = blockIdx.x * 256 + threadIdx.x;
    float a = 1.0f / y18[i];
    float b = 1.0f / y19[i];
    avec[i] = a;
    bvec[i] = b;
    float pv = __uint_as_float(cmax[i]) * b;
    #pragma unroll
    for (int off = 32; off > 0; off >>= 1) pv = fmaxf(pv, __shfl_xor(pv, off));
    __shared__ float lm[4];
    int t = threadIdx.x;
    if ((t & 63) == 0) lm[t >> 6] = pv;
    __syncthreads();
    if (t == 0) atomicMax(gpm, __float_as_uint(fmaxf(fmaxf(lm[0], lm[1]), fmaxf(lm[2], lm[3]))));
}

// ---------------- scp = (1+Pm)/Pm ----------------
__global__ void sc_kernel(const unsigned* __restrict__ gpm, float* __restrict__ scp) {
    float Pm = __uint_as_float(gpm[0]);
    scp[0] = (1.0f + Pm) / Pm;
}

// ---------------- finalize: out = S * P/(1+P), P = a_i E_ij b_j, diag = 1 --------
__launch_bounds__(256)
__global__ void finalize_mult(const _Float16* __restrict__ E, float* __restrict__ out,
                              const float* __restrict__ a, const float* __restrict__ b,
                              const float* __restrict__ scp) {
    float S = scp[0];
    const size_t nt8 = (size_t)NROW * NROW / 8;
    size_t stride = (size_t)gridDim.x * blockDim.x;
    for (size_t e8 = (size_t)blockIdx.x * blockDim.x + threadIdx.x; e8 < nt8; e8 += stride) {
        size_t i = e8 >> 10;                 // 1024 half8 per row
        int j0 = (int)((e8 & 1023) << 3);
        half8 ev = reinterpret_cast<const half8*>(E)[e8];
        float4 b0 = reinterpret_cast<const float4*>(b)[(e8 & 1023) * 2];
        float4 b1 = reinterpret_cast<const float4*>(b)[(e8 & 1023) * 2 + 1];
        float ai = a[i];
        float P[8];
        P[0] = ai * (float)ev[0] * b0.x; P[1] = ai * (float)ev[1] * b0.y;
        P[2] = ai * (float)ev[2] * b0.z; P[3] = ai * (float)ev[3] * b0.w;
        P[4] = ai * (float)ev[4] * b1.x; P[5] = ai * (float)ev[5] * b1.y;
        P[6] = ai * (float)ev[6] * b1.z; P[7] = ai * (float)ev[7] * b1.w;
        float o[8];
        #pragma unroll
        for (int tt = 0; tt < 8; ++tt)
            o[tt] = S * P[tt] * __builtin_amdgcn_rcpf(1.0f + P[tt]);
        if (i >= (size_t)j0 && i < (size_t)j0 + 8) o[i - j0] = 1.0f;
        float4 oa; oa.x = o[0]; oa.y = o[1]; oa.z = o[2]; oa.w = o[3];
        float4 ob; ob.x = o[4]; ob.y = o[5]; ob.z = o[6]; ob.w = o[7];
        reinterpret_cast<float4*>(out)[e8 * 2] = oa;
        reinterpret_cast<float4*>(out)[e8 * 2 + 1] = ob;
    }
}

extern "C" void kernel_launch(void* const* d_in, const int* in_sizes, int n_in,
                              void* d_out, int out_size, void* d_ws, size_t ws_size,
                              hipStream_t stream) {
    const float* X = (const float*)d_in[0];
    float* out = (float*)d_out;
    char* ws = (char*)d_ws;

    size_t off = 0;
    ushort* dn_hi = (ushort*)(ws + off); off += (size_t)NROW * DIM * 2;     // 2 MB
    ushort* dn_lo = (ushort*)(ws + off); off += (size_t)NROW * DIM * 2;     // 2 MB
    float* ybuf   = (float*)(ws + off);  off += (size_t)NPASS * NROW * 4;   // 640 KB
    unsigned* cmax = (unsigned*)(ws + off); off += NROW * 4;
    float* avec   = (float*)(ws + off);  off += NROW * 4;
    float* bvec   = (float*)(ws + off);  off += NROW * 4;
    unsigned* gpm = (unsigned*)(ws + off); off += 64;
    float* scp    = (float*)(ws + off);  off += 64;
    off = (off + 255) & ~(size_t)255;
    _Float16* E = (_Float16*)(ws + off); off += (size_t)NROW * NROW * 2;    // 128 MiB

    init_kernel<<<NPASS * NROW / 256, 256, 0, stream>>>(ybuf, cmax, gpm);
    rownorm_kernel<<<NROW, 64, 0, stream>>>(X, dn_hi, dn_lo);

    dim3 g(NROW / 128, NROW / 128);
    buildE_mfma<<<g, 256, 0, stream>>>(dn_hi, dn_lo, E, ybuf);   // ybuf[0] = E*ones

    for (int p = 1; p < NPASS; ++p) {
        const float* yp = ybuf + (size_t)(p - 1) * NROW;
        float* yn = ybuf + (size_t)p * NROW;
        if (p == NPASS - 1) symv_tri<true ><<<NUNITS, 256, 0, stream>>>(E, yp, yn, cmax);
        else                symv_tri<false><<<NUNITS, 256, 0, stream>>>(E, yp, yn, cmax);
    }

    vecfinish<<<NROW / 256, 256, 0, stream>>>(ybuf + (size_t)(NPASS - 2) * NROW,
                                              ybuf + (size_t)(NPASS - 1) * NROW,
                                              cmax, avec, bvec, gpm);
    sc_kernel<<<1, 1, 0, stream>>>(gpm, scp);
    finalize_mult<<<4096, 256, 0, stream>>>(E, out, avec, bvec, scp);
}